// Round 11
// baseline (189.433 us; speedup 1.0000x reference)
//
#include <hip/hip_runtime.h>
#include <math.h>

// Problem constants
#define NPIX   131072      // B*H*W = 32*64*64
#define KEMB   512
#define DDIM   64
#define HW     4096        // H*W
#define BSTRIDE 262144     // C*H*W

// d_out flat layout (float32): [loss(1) | out(8388608) | perplexity(1) | indices(131072)]
#define OUT_OFF  1
#define PERP_OFF 8388609
#define IDX_OFF  8388610

typedef __attribute__((ext_vector_type(8))) short bf16x8;   // 8 bf16 = 4 VGPRs (MFMA A/B frag)
typedef __attribute__((ext_vector_type(4))) float f32x4;    // MFMA C/D frag

__device__ __forceinline__ unsigned short bf16_rtne(float f) {
    unsigned int u = __float_as_uint(f);
    u += 0x7FFFu + ((u >> 16) & 1u);
    return (unsigned short)(u >> 16);
}
__device__ __forceinline__ float bf16_to_f(unsigned short h) {
    return __uint_as_float(((unsigned int)h) << 16);
}

// 6 split-products per k-step: hh, hm, mh, hl, lh, mm (R5..R9 order — passed)
#define MFMA_STEP(AH, AM, AL, XH, XM, XL, ACC) \
    ACC = __builtin_amdgcn_mfma_f32_16x16x32_bf16(AH, XH, ACC, 0, 0, 0); \
    ACC = __builtin_amdgcn_mfma_f32_16x16x32_bf16(AH, XM, ACC, 0, 0, 0); \
    ACC = __builtin_amdgcn_mfma_f32_16x16x32_bf16(AM, XH, ACC, 0, 0, 0); \
    ACC = __builtin_amdgcn_mfma_f32_16x16x32_bf16(AH, XL, ACC, 0, 0, 0); \
    ACC = __builtin_amdgcn_mfma_f32_16x16x32_bf16(AL, XH, ACC, 0, 0, 0); \
    ACC = __builtin_amdgcn_mfma_f32_16x16x32_bf16(AM, XM, ACC, 0, 0, 0);

// ws layout: [0,2048) int counts | [2048,4096) float hnorms | [4096] loss |
//            [8192) ebh ushort[32768] | +64KB ebm | +64KB ebl
// R9-verbatim init (passed): 512 blocks x 64 threads, block=code, lane=channel.
__global__ void vq_init(const float* __restrict__ emb, int* __restrict__ counts,
                        float* __restrict__ hnorms, float* __restrict__ loss_acc,
                        unsigned short* __restrict__ ebh, unsigned short* __restrict__ ebm,
                        unsigned short* __restrict__ ebl) {
    const int k = blockIdx.x;
    const int c = threadIdx.x;
    float x = emb[k * DDIM + c];
    unsigned short h = bf16_rtne(x);
    float r1 = x - bf16_to_f(h);          // exact (Sterbenz)
    unsigned short m = bf16_rtne(r1);
    float r2 = r1 - bf16_to_f(m);         // exact
    unsigned short l = bf16_rtne(r2);
    ebh[k * DDIM + c] = h; ebm[k * DDIM + c] = m; ebl[k * DDIM + c] = l;
    float s = x * x;
#pragma unroll
    for (int off = 1; off <= 32; off <<= 1) s += __shfl_xor(s, off, 64);
    if (c == 0) {
        hnorms[k] = 0.5f * s;
        counts[k] = 0;
        if (k == 0) *loss_acc = 0.f;
    }
}

// One 1024-thread block per CU (256 blocks). h+m split tables (128 KB) + hnorms
// + hist all in LDS; K-loop is BARRIER-FREE (16 waves free-run). Only the Al
// fragments (1 of 6 products) come from global/L2, with one-tile prefetch.
__global__ __launch_bounds__(1024) void vq_main(
    const float* __restrict__ in, const float* __restrict__ emb,
    const unsigned short* __restrict__ ebh, const unsigned short* __restrict__ ebm,
    const unsigned short* __restrict__ ebl,
    const float* __restrict__ hnorms, int* __restrict__ counts,
    float* __restrict__ loss_acc, float* __restrict__ dout)
{
    __shared__ __align__(16) unsigned short ebh_l[KEMB * DDIM];  // 64 KB
    __shared__ __align__(16) unsigned short ebm_l[KEMB * DDIM];  // 64 KB
    __shared__ __align__(16) float hn_lds[KEMB];                 // 2 KB
    __shared__ int hist[KEMB];                                   // 2 KB

    const int t    = threadIdx.x;         // 0..1023
    const int lane = t & 63;
    const int wv   = t >> 6;              // wave id 0..15
    const int quad = lane >> 4;
    const int col  = lane & 15;
    const int b    = blockIdx.x >> 3;                        // 8 blocks per image
    const int p0   = ((blockIdx.x & 7) << 9) | (wv << 5);    // first of this wave's 32 px
    const float* xb = in + b * BSTRIDE;

    if (t < KEMB) hist[t] = 0;
    if (t < 128) ((float4*)hn_lds)[t] = ((const float4*)hnorms)[t];

    // ---- Stage h,m tables into LDS in fragment order (R7-proven mapping).
    // Fragment f=(ct,ks,lf): code ct*16+(lf&15), channels ks*32+(lf>>4)*8.
#pragma unroll
    for (int i = 0; i < 4; ++i) {
        const int f  = t + i * 1024;
        const int ct = f >> 7;
        const int ks = (f >> 6) & 1;
        const int lf = f & 63;
        const int src = (ct * 16 + (lf & 15)) * DDIM + ks * 32 + (lf >> 4) * 8;
        const int dst = ct * 1024 + ks * 512 + lf * 8;
        *(bf16x8*)&ebh_l[dst] = *(const bf16x8*)(ebh + src);
        *(bf16x8*)&ebm_l[dst] = *(const bf16x8*)(ebm + src);
    }

    // ---- Build x B-fragments: B[n=col][k=quad*8+j], xf[split][ptile][kstep]
    bf16x8 xf[3][2][2];
#pragma unroll
    for (int tt = 0; tt < 2; ++tt) {
#pragma unroll
        for (int s = 0; s < 2; ++s) {
            const int pp = p0 + tt * 16 + col;
            const int c0 = s * 32 + quad * 8;
            bf16x8 vh, vm, vl;
#pragma unroll
            for (int j = 0; j < 8; ++j) {
                float x = xb[(c0 + j) * HW + pp];
                unsigned short h = bf16_rtne(x);
                float r1 = x - bf16_to_f(h);
                unsigned short m = bf16_rtne(r1);
                float r2 = r1 - bf16_to_f(m);
                unsigned short l = bf16_rtne(r2);
                vh[j] = (short)h; vm[j] = (short)m; vl[j] = (short)l;
            }
            xf[0][tt][s] = vh; xf[1][tt][s] = vm; xf[2][tt][s] = vl;
        }
    }

    __syncthreads();   // staging done; K-loop below is barrier-free

    // ---- K-loop over 32 code tiles
    const int arow = col * DDIM + quad * 8;   // Al per-lane offset within a tile
    float v1[2], v2[2]; int k1[2], k2[2];
#pragma unroll
    for (int tt = 0; tt < 2; ++tt) {
        v1[tt] = 3.402823466e38f; v2[tt] = 3.402823466e38f; k1[tt] = 0; k2[tt] = 0;
    }

    bf16x8 Al0 = *(const bf16x8*)(ebl + arow);
    bf16x8 Al1 = *(const bf16x8*)(ebl + arow + 32);

    for (int ct = 0; ct < 32; ++ct) {
        // Prefetch next tile's Al fragments (drains under this tile's MFMAs)
        bf16x8 Al0n, Al1n;
        if (ct < 31) {
            const int sb = (ct + 1) * 1024 + arow;
            Al0n = *(const bf16x8*)(ebl + sb);
            Al1n = *(const bf16x8*)(ebl + sb + 32);
        }

        const int base = ct * 1024 + lane * 8;
        const bf16x8 Ah0 = *(const bf16x8*)&ebh_l[base];
        const bf16x8 Ah1 = *(const bf16x8*)&ebh_l[base + 512];
        const bf16x8 Am0 = *(const bf16x8*)&ebm_l[base];
        const bf16x8 Am1 = *(const bf16x8*)&ebm_l[base + 512];

        f32x4 acc0 = (f32x4){0.f, 0.f, 0.f, 0.f};
        f32x4 acc1 = (f32x4){0.f, 0.f, 0.f, 0.f};
        MFMA_STEP(Ah0, Am0, Al0, xf[0][0][0], xf[1][0][0], xf[2][0][0], acc0)
        MFMA_STEP(Ah1, Am1, Al1, xf[0][0][1], xf[1][0][1], xf[2][0][1], acc0)
        MFMA_STEP(Ah0, Am0, Al0, xf[0][1][0], xf[1][1][0], xf[2][1][0], acc1)
        MFMA_STEP(Ah1, Am1, Al1, xf[0][1][1], xf[1][1][1], xf[2][1][1], acc1)

        const f32x4 hn = *(const f32x4*)&hn_lds[ct * 16 + quad * 4];
#pragma unroll
        for (int r = 0; r < 4; ++r) {
            const int kk = ct * 16 + quad * 4 + r;
            float sc = hn[r] - acc0[r];
            if (sc < v1[0]) { v2[0] = v1[0]; k2[0] = k1[0]; v1[0] = sc; k1[0] = kk; }
            else if (sc < v2[0]) { v2[0] = sc; k2[0] = kk; }
            sc = hn[r] - acc1[r];
            if (sc < v1[1]) { v2[1] = v1[1]; k2[1] = k1[1]; v1[1] = sc; k1[1] = kk; }
            else if (sc < v2[1]) { v2[1] = sc; k2[1] = kk; }
        }

        Al0 = Al0n; Al1 = Al1n;
    }

    // Cross-quad top-2 merge (lanes l, l^16, l^32 share pixel-col) — R6 verbatim
#pragma unroll
    for (int tt = 0; tt < 2; ++tt) {
#pragma unroll
        for (int off = 16; off <= 32; off <<= 1) {
            float w1 = __shfl_xor(v1[tt], off, 64); int j1 = __shfl_xor(k1[tt], off, 64);
            float w2 = __shfl_xor(v2[tt], off, 64); int j2 = __shfl_xor(k2[tt], off, 64);
            bool aF = (v1[tt] < w1) || (v1[tt] == w1 && k1[tt] < j1);
            float t1 = aF ? v1[tt] : w1;  int u1 = aF ? k1[tt] : j1;
            float tl = aF ? w1 : v1[tt];  int ul = aF ? j1 : k1[tt];      // loser of firsts
            bool bS = (v2[tt] < w2) || (v2[tt] == w2 && k2[tt] < j2);
            float tc = bS ? v2[tt] : w2;  int uc = bS ? k2[tt] : j2;      // better of seconds
            bool lS = (tl < tc) || (tl == tc && ul < uc);
            v1[tt] = t1; k1[tt] = u1;
            v2[tt] = lS ? tl : tc; k2[tt] = lS ? ul : uc;
        }
    }

    // Pixel q = lane&31; lanes l and l+32 handle the same pixel (tt = (l>>4)&1).
    const int q    = lane & 31;
    const int pp   = p0 + q;
    const int tsel = (lane >> 4) & 1;
    const int kA = tsel ? k1[1] : k1[0];
    const int kB = tsel ? k2[1] : k2[0];

    // Reload x (fp32, coalesced) for exact rescore + epilogue
    float x[DDIM];
#pragma unroll
    for (int c = 0; c < DDIM; ++c) x[c] = xb[c * HW + pp];

    // Exact fp32 rescore, split: lanes<32 score kA, lanes>=32 score kB.
    // Per-code chain byte-identical to the R5..R9-passing kernels.
    const int kMine = (lane < 32) ? kA : kB;
    const float4* eM = (const float4*)(emb + kMine * DDIM);
    float a0 = hn_lds[kMine], a1 = 0.f, a2 = 0.f, a3 = 0.f;
#pragma unroll
    for (int i = 0; i < 16; ++i) {
        float4 ea = eM[i];
        const int c = i * 4;
        a0 = fmaf(-x[c + 0], ea.x, a0);
        a1 = fmaf(-x[c + 1], ea.y, a1);
        a2 = fmaf(-x[c + 2], ea.z, a2);
        a3 = fmaf(-x[c + 3], ea.w, a3);
    }
    const float dMine = (a0 + a1) + (a2 + a3);
    const float dOth  = __shfl_xor(dMine, 32, 64);
    const float dA = (lane < 32) ? dMine : dOth;
    const float dB = (lane < 32) ? dOth  : dMine;
    const int myk = (dB < dA || (dB == dA && kB < kA)) ? kB : kA;

    float lsum = 0.f;
    if (lane < 32) {
        dout[IDX_OFF + b * HW + pp] = (float)myk;
        atomicAdd(&hist[myk], 1);
        const float4* qrow = (const float4*)(emb + myk * DDIM);
        float* ob = dout + OUT_OFF + b * BSTRIDE;
#pragma unroll
        for (int i = 0; i < 16; ++i) {
            float4 qv = qrow[i];
            const int c = i * 4;
            float d0 = qv.x - x[c + 0];
            float d1 = qv.y - x[c + 1];
            float d2 = qv.z - x[c + 2];
            float d3 = qv.w - x[c + 3];
            lsum += d0 * d0 + d1 * d1 + d2 * d2 + d3 * d3;
            ob[(c + 0) * HW + pp] = x[c + 0] + d0;   // reference rounding: x + (q - x)
            ob[(c + 1) * HW + pp] = x[c + 1] + d1;
            ob[(c + 2) * HW + pp] = x[c + 2] + d2;
            ob[(c + 3) * HW + pp] = x[c + 3] + d3;
        }
    }
    for (int off = 32; off > 0; off >>= 1) lsum += __shfl_down(lsum, off, 64);
    if (lane == 0) atomicAdd(loss_acc, lsum);

    __syncthreads();
    if (t < KEMB) {
        int v = hist[t];
        if (v) atomicAdd(&counts[t], v);
    }
}

__global__ void vq_fin(const int* __restrict__ counts,
                       const float* __restrict__ loss_acc,
                       float* __restrict__ dout) {
    __shared__ float part[8];
    const int k = threadIdx.x;            // 512 threads = 8 waves
    float pa = (float)counts[k] / (float)NPIX;
    float v = pa * logf(pa + 1e-10f);
#pragma unroll
    for (int off = 1; off <= 32; off <<= 1) v += __shfl_xor(v, off, 64);
    if ((k & 63) == 0) part[k >> 6] = v;
    __syncthreads();
    if (k == 0) {
        float s = 0.f;
#pragma unroll
        for (int i = 0; i < 8; ++i) s += part[i];
        dout[PERP_OFF] = expf(-s);
        dout[0] = 0.25f * (*loss_acc) / 8388608.0f;
    }
}

extern "C" void kernel_launch(void* const* d_in, const int* in_sizes, int n_in,
                              void* d_out, int out_size, void* d_ws, size_t ws_size,
                              hipStream_t stream) {
    const float* in  = (const float*)d_in[0];   // 8388608 elems
    const float* emb = (const float*)d_in[1];   // 32768 elems
    float* dout = (float*)d_out;
    int*   counts   = (int*)d_ws;
    float* hnorms   = (float*)((char*)d_ws + 2048);
    float* loss_acc = (float*)((char*)d_ws + 4096);
    unsigned short* ebh = (unsigned short*)((char*)d_ws + 8192);
    unsigned short* ebm = ebh + KEMB * DDIM;
    unsigned short* ebl = ebm + KEMB * DDIM;

    vq_init<<<512, 64, 0, stream>>>(emb, counts, hnorms, loss_acc, ebh, ebm, ebl);
    vq_main<<<256, 1024, 0, stream>>>(in, emb, ebh, ebm, ebl, hnorms, counts, loss_acc, dout);
    vq_fin<<<1, 512, 0, stream>>>(counts, loss_acc, dout);
}

// Round 12
// 176.465 us; speedup vs baseline: 1.0735x; 1.0735x over previous
//
#include <hip/hip_runtime.h>
#include <math.h>

// Problem constants
#define NPIX   131072      // B*H*W = 32*64*64
#define KEMB   512
#define DDIM   64
#define HW     4096        // H*W
#define BSTRIDE 262144     // C*H*W

// d_out flat layout (float32): [loss(1) | out(8388608) | perplexity(1) | indices(131072)]
#define OUT_OFF  1
#define PERP_OFF 8388609
#define IDX_OFF  8388610

typedef __attribute__((ext_vector_type(8))) short bf16x8;   // 8 bf16 = 4 VGPRs (MFMA A/B frag)
typedef __attribute__((ext_vector_type(4))) float f32x4;    // MFMA C/D frag

__device__ __forceinline__ unsigned short bf16_rtne(float f) {
    unsigned int u = __float_as_uint(f);
    u += 0x7FFFu + ((u >> 16) & 1u);
    return (unsigned short)(u >> 16);
}
__device__ __forceinline__ float bf16_to_f(unsigned short h) {
    return __uint_as_float(((unsigned int)h) << 16);
}

// 6 split-products per k-step: hh, hm, mh, hl, lh, mm (R5..R11 order — passed)
#define MFMA_STEP(AH, AM, AL, XH, XM, XL, ACC) \
    ACC = __builtin_amdgcn_mfma_f32_16x16x32_bf16(AH, XH, ACC, 0, 0, 0); \
    ACC = __builtin_amdgcn_mfma_f32_16x16x32_bf16(AH, XM, ACC, 0, 0, 0); \
    ACC = __builtin_amdgcn_mfma_f32_16x16x32_bf16(AM, XH, ACC, 0, 0, 0); \
    ACC = __builtin_amdgcn_mfma_f32_16x16x32_bf16(AH, XL, ACC, 0, 0, 0); \
    ACC = __builtin_amdgcn_mfma_f32_16x16x32_bf16(AL, XH, ACC, 0, 0, 0); \
    ACC = __builtin_amdgcn_mfma_f32_16x16x32_bf16(AM, XM, ACC, 0, 0, 0);

// ws layout: [0,2048) int counts | [2048,4096) float hnorms | [4096] loss |
//            [8192) ebh ushort[32768] | +64KB ebm | +64KB ebl
// R9/R11-verbatim init (passed): 512 blocks x 64 threads, block=code, lane=channel.
__global__ void vq_init(const float* __restrict__ emb, int* __restrict__ counts,
                        float* __restrict__ hnorms, float* __restrict__ loss_acc,
                        unsigned short* __restrict__ ebh, unsigned short* __restrict__ ebm,
                        unsigned short* __restrict__ ebl) {
    const int k = blockIdx.x;
    const int c = threadIdx.x;
    float x = emb[k * DDIM + c];
    unsigned short h = bf16_rtne(x);
    float r1 = x - bf16_to_f(h);          // exact (Sterbenz)
    unsigned short m = bf16_rtne(r1);
    float r2 = r1 - bf16_to_f(m);         // exact
    unsigned short l = bf16_rtne(r2);
    ebh[k * DDIM + c] = h; ebm[k * DDIM + c] = m; ebl[k * DDIM + c] = l;
    float s = x * x;
#pragma unroll
    for (int off = 1; off <= 32; off <<= 1) s += __shfl_xor(s, off, 64);
    if (c == 0) {
        hnorms[k] = 0.5f * s;
        counts[k] = 0;
        if (k == 0) *loss_acc = 0.f;
    }
}

// One 1024-thread block per CU (256 blocks). h+m split tables (128 KB) + hnorms
// + hist in LDS; K-loop is BARRIER-FREE (16 waves free-run). Al fragments (1 of
// 6 products) come from the L2-resident 64-KB global table with 1-tile prefetch.
// launch_bounds(1024,4): VGPR cap exactly 128. NO x[64] array in the epilogue —
// R11's x[64] forced a 64-VGPR cap and ~130 MB of scratch spill traffic.
__global__ __launch_bounds__(1024, 4) void vq_main(
    const float* __restrict__ in, const float* __restrict__ emb,
    const unsigned short* __restrict__ ebh, const unsigned short* __restrict__ ebm,
    const unsigned short* __restrict__ ebl,
    const float* __restrict__ hnorms, int* __restrict__ counts,
    float* __restrict__ loss_acc, float* __restrict__ dout)
{
    __shared__ __align__(16) unsigned short ebh_l[KEMB * DDIM];  // 64 KB
    __shared__ __align__(16) unsigned short ebm_l[KEMB * DDIM];  // 64 KB
    __shared__ __align__(16) float hn_lds[KEMB];                 // 2 KB
    __shared__ int hist[KEMB];                                   // 2 KB

    const int t    = threadIdx.x;         // 0..1023
    const int lane = t & 63;
    const int wv   = t >> 6;              // wave id 0..15
    const int quad = lane >> 4;
    const int col  = lane & 15;
    const int b    = blockIdx.x >> 3;                        // 8 blocks per image
    const int p0   = ((blockIdx.x & 7) << 9) | (wv << 5);    // first of this wave's 32 px
    const float* xb = in + b * BSTRIDE;

    if (t < KEMB) hist[t] = 0;
    if (t < 128) ((float4*)hn_lds)[t] = ((const float4*)hnorms)[t];

    // ---- Stage h,m tables into LDS in fragment order (R7-proven mapping).
#pragma unroll
    for (int i = 0; i < 4; ++i) {
        const int f  = t + i * 1024;
        const int ct = f >> 7;
        const int ks = (f >> 6) & 1;
        const int lf = f & 63;
        const int src = (ct * 16 + (lf & 15)) * DDIM + ks * 32 + (lf >> 4) * 8;
        const int dst = ct * 1024 + ks * 512 + lf * 8;
        *(bf16x8*)&ebh_l[dst] = *(const bf16x8*)(ebh + src);
        *(bf16x8*)&ebm_l[dst] = *(const bf16x8*)(ebm + src);
    }

    // ---- Build x B-fragments: B[n=col][k=quad*8+j], xf[split][ptile][kstep]
    bf16x8 xf[3][2][2];
#pragma unroll
    for (int tt = 0; tt < 2; ++tt) {
#pragma unroll
        for (int s = 0; s < 2; ++s) {
            const int pp = p0 + tt * 16 + col;
            const int c0 = s * 32 + quad * 8;
            bf16x8 vh, vm, vl;
#pragma unroll
            for (int j = 0; j < 8; ++j) {
                float x = xb[(c0 + j) * HW + pp];
                unsigned short h = bf16_rtne(x);
                float r1 = x - bf16_to_f(h);
                unsigned short m = bf16_rtne(r1);
                float r2 = r1 - bf16_to_f(m);
                unsigned short l = bf16_rtne(r2);
                vh[j] = (short)h; vm[j] = (short)m; vl[j] = (short)l;
            }
            xf[0][tt][s] = vh; xf[1][tt][s] = vm; xf[2][tt][s] = vl;
        }
    }

    __syncthreads();   // staging done; K-loop below is barrier-free

    // ---- K-loop over 32 code tiles
    const int arow = col * DDIM + quad * 8;   // Al per-lane offset within a tile
    float v1[2], v2[2]; int k1[2], k2[2];
#pragma unroll
    for (int tt = 0; tt < 2; ++tt) {
        v1[tt] = 3.402823466e38f; v2[tt] = 3.402823466e38f; k1[tt] = 0; k2[tt] = 0;
    }

    bf16x8 Al0 = *(const bf16x8*)(ebl + arow);
    bf16x8 Al1 = *(const bf16x8*)(ebl + arow + 32);

    for (int ct = 0; ct < 32; ++ct) {
        // Prefetch next tile's Al fragments (drains under this tile's MFMAs)
        bf16x8 Al0n, Al1n;
        if (ct < 31) {
            const int sb = (ct + 1) * 1024 + arow;
            Al0n = *(const bf16x8*)(ebl + sb);
            Al1n = *(const bf16x8*)(ebl + sb + 32);
        }

        const int base = ct * 1024 + lane * 8;
        const bf16x8 Ah0 = *(const bf16x8*)&ebh_l[base];
        const bf16x8 Ah1 = *(const bf16x8*)&ebh_l[base + 512];
        const bf16x8 Am0 = *(const bf16x8*)&ebm_l[base];
        const bf16x8 Am1 = *(const bf16x8*)&ebm_l[base + 512];

        f32x4 acc0 = (f32x4){0.f, 0.f, 0.f, 0.f};
        f32x4 acc1 = (f32x4){0.f, 0.f, 0.f, 0.f};
        MFMA_STEP(Ah0, Am0, Al0, xf[0][0][0], xf[1][0][0], xf[2][0][0], acc0)
        MFMA_STEP(Ah1, Am1, Al1, xf[0][0][1], xf[1][0][1], xf[2][0][1], acc0)
        MFMA_STEP(Ah0, Am0, Al0, xf[0][1][0], xf[1][1][0], xf[2][1][0], acc1)
        MFMA_STEP(Ah1, Am1, Al1, xf[0][1][1], xf[1][1][1], xf[2][1][1], acc1)

        const f32x4 hn = *(const f32x4*)&hn_lds[ct * 16 + quad * 4];
#pragma unroll
        for (int r = 0; r < 4; ++r) {
            const int kk = ct * 16 + quad * 4 + r;
            float sc = hn[r] - acc0[r];
            if (sc < v1[0]) { v2[0] = v1[0]; k2[0] = k1[0]; v1[0] = sc; k1[0] = kk; }
            else if (sc < v2[0]) { v2[0] = sc; k2[0] = kk; }
            sc = hn[r] - acc1[r];
            if (sc < v1[1]) { v2[1] = v1[1]; k2[1] = k1[1]; v1[1] = sc; k1[1] = kk; }
            else if (sc < v2[1]) { v2[1] = sc; k2[1] = kk; }
        }

        Al0 = Al0n; Al1 = Al1n;
    }

    // Cross-quad top-2 merge (lanes l, l^16, l^32 share pixel-col) — R6 verbatim
#pragma unroll
    for (int tt = 0; tt < 2; ++tt) {
#pragma unroll
        for (int off = 16; off <= 32; off <<= 1) {
            float w1 = __shfl_xor(v1[tt], off, 64); int j1 = __shfl_xor(k1[tt], off, 64);
            float w2 = __shfl_xor(v2[tt], off, 64); int j2 = __shfl_xor(k2[tt], off, 64);
            bool aF = (v1[tt] < w1) || (v1[tt] == w1 && k1[tt] < j1);
            float t1 = aF ? v1[tt] : w1;  int u1 = aF ? k1[tt] : j1;
            float tl = aF ? w1 : v1[tt];  int ul = aF ? j1 : k1[tt];      // loser of firsts
            bool bS = (v2[tt] < w2) || (v2[tt] == w2 && k2[tt] < j2);
            float tc = bS ? v2[tt] : w2;  int uc = bS ? k2[tt] : j2;      // better of seconds
            bool lS = (tl < tc) || (tl == tc && ul < uc);
            v1[tt] = t1; k1[tt] = u1;
            v2[tt] = lS ? tl : tc; k2[tt] = lS ? ul : uc;
        }
    }

    // Pixel q = lane&31; lanes l and l+32 handle the same pixel (tt = (l>>4)&1).
    const int q    = lane & 31;
    const int pp   = p0 + q;
    const int tsel = (lane >> 4) & 1;
    const int kA = tsel ? k1[1] : k1[0];
    const int kB = tsel ? k2[1] : k2[0];

    // Exact fp32 rescore, split: lanes<32 score kA, lanes>=32 score kB.
    // Streaming x loads (no x[64] array!) — ops and order bitwise == R11 chain.
    const int kMine = (lane < 32) ? kA : kB;
    const float4* eM = (const float4*)(emb + kMine * DDIM);
    float a0 = hn_lds[kMine], a1 = 0.f, a2 = 0.f, a3 = 0.f;
#pragma unroll
    for (int i = 0; i < 16; ++i) {
        float4 ea = eM[i];
        const int c = i * 4;
        float x0 = xb[(c + 0) * HW + pp];
        float x1 = xb[(c + 1) * HW + pp];
        float x2 = xb[(c + 2) * HW + pp];
        float x3 = xb[(c + 3) * HW + pp];
        a0 = fmaf(-x0, ea.x, a0);
        a1 = fmaf(-x1, ea.y, a1);
        a2 = fmaf(-x2, ea.z, a2);
        a3 = fmaf(-x3, ea.w, a3);
    }
    const float dMine = (a0 + a1) + (a2 + a3);
    const float dOth  = __shfl_xor(dMine, 32, 64);
    const float dA = (lane < 32) ? dMine : dOth;
    const float dB = (lane < 32) ? dOth  : dMine;
    const int myk = (dB < dA || (dB == dA && kB < kA)) ? kB : kA;

    float lsum = 0.f;
    if (lane < 32) {
        dout[IDX_OFF + b * HW + pp] = (float)myk;
        atomicAdd(&hist[myk], 1);
        const float4* qrow = (const float4*)(emb + myk * DDIM);
        float* ob = dout + OUT_OFF + b * BSTRIDE;
#pragma unroll
        for (int i = 0; i < 16; ++i) {
            float4 qv = qrow[i];
            const int c = i * 4;
            float x0 = xb[(c + 0) * HW + pp];   // L1-warm reload (just read above)
            float x1 = xb[(c + 1) * HW + pp];
            float x2 = xb[(c + 2) * HW + pp];
            float x3 = xb[(c + 3) * HW + pp];
            float d0 = qv.x - x0;
            float d1 = qv.y - x1;
            float d2 = qv.z - x2;
            float d3 = qv.w - x3;
            lsum += d0 * d0 + d1 * d1 + d2 * d2 + d3 * d3;
            ob[(c + 0) * HW + pp] = x0 + d0;    // reference rounding: x + (q - x)
            ob[(c + 1) * HW + pp] = x1 + d1;
            ob[(c + 2) * HW + pp] = x2 + d2;
            ob[(c + 3) * HW + pp] = x3 + d3;
        }
    }
    for (int off = 32; off > 0; off >>= 1) lsum += __shfl_down(lsum, off, 64);
    if (lane == 0) atomicAdd(loss_acc, lsum);

    __syncthreads();
    if (t < KEMB) {
        int v = hist[t];
        if (v) atomicAdd(&counts[t], v);
    }
}

__global__ void vq_fin(const int* __restrict__ counts,
                       const float* __restrict__ loss_acc,
                       float* __restrict__ dout) {
    __shared__ float part[8];
    const int k = threadIdx.x;            // 512 threads = 8 waves
    float pa = (float)counts[k] / (float)NPIX;
    float v = pa * logf(pa + 1e-10f);
#pragma unroll
    for (int off = 1; off <= 32; off <<= 1) v += __shfl_xor(v, off, 64);
    if ((k & 63) == 0) part[k >> 6] = v;
    __syncthreads();
    if (k == 0) {
        float s = 0.f;
#pragma unroll
        for (int i = 0; i < 8; ++i) s += part[i];
        dout[PERP_OFF] = expf(-s);
        dout[0] = 0.25f * (*loss_acc) / 8388608.0f;
    }
}

extern "C" void kernel_launch(void* const* d_in, const int* in_sizes, int n_in,
                              void* d_out, int out_size, void* d_ws, size_t ws_size,
                              hipStream_t stream) {
    const float* in  = (const float*)d_in[0];   // 8388608 elems
    const float* emb = (const float*)d_in[1];   // 32768 elems
    float* dout = (float*)d_out;
    int*   counts   = (int*)d_ws;
    float* hnorms   = (float*)((char*)d_ws + 2048);
    float* loss_acc = (float*)((char*)d_ws + 4096);
    unsigned short* ebh = (unsigned short*)((char*)d_ws + 8192);
    unsigned short* ebm = ebh + KEMB * DDIM;
    unsigned short* ebl = ebm + KEMB * DDIM;

    vq_init<<<512, 64, 0, stream>>>(emb, counts, hnorms, loss_acc, ebh, ebm, ebl);
    vq_main<<<256, 1024, 0, stream>>>(in, emb, ebh, ebm, ebl, hnorms, counts, loss_acc, dout);
    vq_fin<<<1, 512, 0, stream>>>(counts, loss_acc, dout);
}